// Round 12
// baseline (561.659 us; speedup 1.0000x reference)
//
#include <hip/hip_runtime.h>

#define NPTS 2048
#define BATCH 4
#define CFEAT 64
#define MCENT 512

typedef float f4 __attribute__((ext_vector_type(4)));
typedef float f2 __attribute__((ext_vector_type(2)));
typedef short s8v __attribute__((ext_vector_type(8)));

__device__ __forceinline__ unsigned short f2bf(float x) {
    unsigned u = __float_as_uint(x);
    return (unsigned short)((u + 0x7fffu + ((u >> 16) & 1u)) >> 16);
}

template <int CTRL>
__device__ __forceinline__ float dpp_max_step(float v) {
    int t = __builtin_amdgcn_update_dpp(0, __float_as_int(v), CTRL, 0xf, 0xf, true);
    return fmaxf(v, __int_as_float(t));
}

__device__ __forceinline__ float readlane_f(float v, int l) {
    return __int_as_float(__builtin_amdgcn_readlane(__float_as_int(v), l));
}

// ---------------- weight packing (bf16, padded, layer0 column-permuted) ----------------
// wp (ushort elems): s0l0@0 (64x96), s0l1@6144 (64x64), s0l2@10240 (128x64),
// s1l0@18432 (128x96), s1l1@30720 (128x128), s1l2@47104 (256x128) -> 79872
template <int COUT, int CIN, int KPW, bool PERM>
__device__ void pack_seg(const float* w, unsigned short* dst, int start, int stride) {
    for (int i = start; i < COUT * KPW; i += stride) {
        int o = i / KPW, k = i - o * KPW;
        float v = 0.f;
        if (PERM) {  // packed col k: [0,64)=feat(src 3+k), [64,67)=xyz(src k-64), rest 0
            if (k < 64) v = w[o * CIN + 3 + k];
            else if (k < 67) v = w[o * CIN + (k - 64)];
        } else {
            if (k < CIN) v = w[o * CIN + k];
        }
        dst[i] = f2bf(v);
    }
}

// ---------------- FPS: block 0 = 4 chains x 4 waves on ONE CU; blocks 1..64 prep ----------------
__global__ __launch_bounds__(1024, 1) void fps_prep(
    const float* __restrict__ pts, const float* __restrict__ feats,
    const float* w00, const float* w01, const float* w02,
    const float* w10, const float* w11, const float* w12,
    float* cent, unsigned short* ftr, unsigned short* wp, float* out)
{
    const int tid = threadIdx.x;
    if (blockIdx.x >= 1) {
        const int stride = 64 * 1024;
        const int start = (blockIdx.x - 1) * 1024 + tid;
        for (int i = start; i < BATCH * NPTS * CFEAT; i += stride) {
            int c = i & 63, n = (i >> 6) & (NPTS - 1), b = i >> 17;
            ftr[i] = f2bf(feats[(b * CFEAT + c) * NPTS + n]);
        }
        pack_seg<64, 67, 96, true>(w00, wp + 0, start, stride);
        pack_seg<64, 64, 64, false>(w01, wp + 6144, start, stride);
        pack_seg<128, 64, 64, false>(w02, wp + 10240, start, stride);
        pack_seg<128, 67, 96, true>(w10, wp + 18432, start, stride);
        pack_seg<128, 128, 128, false>(w11, wp + 30720, start, stride);
        pack_seg<256, 128, 128, false>(w12, wp + 47104, start, stride);
        return;
    }
    // 16 waves: chain c = wv>>2 (batch), w4 = wv&3 (wave within chain)
    const int lane = tid & 63, wv = tid >> 6;
    const int c = wv >> 2, w4 = wv & 3;
    const float* px = pts + c * 3 * NPTS;
    const float* py = px + NPTS;
    const float* pz = py + NPTS;
    __shared__ __align__(16) float4 scent[BATCH][MCENT];   // 32 KB centroid shadows
    __shared__ __align__(16) float4 slotq[BATCH][2][8];    // [chain][parity][w4*2] (stride-2)

    __builtin_amdgcn_s_setprio(3);   // protect FPS issue while prep may co-reside

    // wave w4 of chain c owns points [w4*512, w4*512+512); lane owns 8 (4 f2 pairs)
    const int base = w4 * 512 + lane * 8;
    f2 rx[4], ry[4], rz[4], rd[4];
#pragma unroll
    for (int i = 0; i < 4; ++i) {
        rx[i] = *(const f2*)(px + base + 2 * i);
        ry[i] = *(const f2*)(py + base + 2 * i);
        rz[i] = *(const f2*)(pz + base + 2 * i);
        rd[i] = (f2){1e10f, 1e10f};
    }
    float cx = px[0], cy = py[0], cz = pz[0];
    int par = 0;
    for (int m = 0; m < MCENT; ++m) {
        if (lane == 0 && w4 == 0) scent[c][m] = make_float4(cx, cy, cz, 0.f);  // LDS only
        {
#pragma clang fp contract(off)
            f2 c2x = {cx, cx}, c2y = {cy, cy}, c2z = {cz, cz};
#pragma unroll
            for (int i = 0; i < 4; ++i) {
                f2 dx = rx[i] - c2x, dy = ry[i] - c2y, dz = rz[i] - c2z;
                f2 d2 = dx * dx + dy * dy;   // contract off: numpy order
                d2 = d2 + dz * dz;
                f2 old = rd[i];
                f2 nd;
                nd.x = fminf(old.x, d2.x);
                nd.y = fminf(old.y, d2.y);
                rd[i] = nd;
            }
        }
        // value-only max tree over lane's 8 points (depth 3)
        float n0 = rd[0].x, n1 = rd[0].y, n2 = rd[1].x, n3 = rd[1].y;
        float n4 = rd[2].x, n5 = rd[2].y, n6 = rd[3].x, n7 = rd[3].y;
        float bv = fmaxf(fmaxf(fmaxf(n0, n1), fmaxf(n2, n3)),
                         fmaxf(fmaxf(n4, n5), fmaxf(n6, n7)));
        // coord select: descending-k scan -> smallest matching k wins (off critical path)
        float ox = rx[3].y, oy = ry[3].y, oz = rz[3].y;
        {
            float ndv[8] = {n0, n1, n2, n3, n4, n5, n6, n7};
#pragma unroll
            for (int k = 6; k >= 0; --k) {
                bool t = (ndv[k] == bv);
                float nx = (k & 1) ? rx[k >> 1].y : rx[k >> 1].x;
                float ny = (k & 1) ? ry[k >> 1].y : ry[k >> 1].x;
                float nz = (k & 1) ? rz[k >> 1].y : rz[k >> 1].x;
                ox = t ? nx : ox; oy = t ? ny : oy; oz = t ? nz : oz;
            }
        }
        // DPP wave max -> lane 63
        float v = bv;
        v = dpp_max_step<0x111>(v);
        v = dpp_max_step<0x112>(v);
        v = dpp_max_step<0x114>(v);
        v = dpp_max_step<0x118>(v);
        v = dpp_max_step<0x142>(v);
        v = dpp_max_step<0x143>(v);
        float wmax = readlane_f(v, 63);
        unsigned long long cand = __ballot(bv == wmax);
        int wl = __ffsll(cand) - 1;          // lowest lane = smallest global index
        if (lane == wl) slotq[c][par][w4 * 2] = make_float4(bv, ox, oy, oz);
        __syncthreads();                      // lockstep barrier for all 4 chains
        float4 s0 = slotq[c][par][0];
        float4 s1 = slotq[c][par][2];
        float4 s2 = slotq[c][par][4];
        float4 s3 = slotq[c][par][6];
        // tie-break = wave order = index order; strict > keeps lower wave on tie
        float4 c01 = (s1.x > s0.x) ? s1 : s0;
        float4 c23 = (s3.x > s2.x) ? s3 : s2;
        float4 cc  = (c23.x > c01.x) ? c23 : c01;
        cx = cc.y; cy = cc.z; cz = cc.w;
        par ^= 1;
    }
    __syncthreads();
    // bulk write centroids (cent for msg kernel, out for result)
    for (int i = tid; i < BATCH * MCENT; i += 1024) {
        int c2 = i >> 9, m = i & (MCENT - 1);
        float4 cc = scent[c2][m];
        float* cw = cent + (c2 * MCENT + m) * 3;
        cw[0] = cc.x; cw[1] = cc.y; cw[2] = cc.z;
        float* outc = out + c2 * 3 * MCENT;
        outc[m] = cc.x; outc[MCENT + m] = cc.y; outc[2 * MCENT + m] = cc.z;
    }
}

// ---------------- MFMA MLP layer ----------------
template <int MT, int KSTEPS, int NTW>
__device__ __forceinline__ void layer_mm(const unsigned short* A, const unsigned short* __restrict__ Wg,
                                         const float* __restrict__ bias, int lane, int wv,
                                         f4 (&acc)[MT][NTW])
{
    constexpr int KP = KSTEPS * 32;
    const int r15 = lane & 15, g = lane >> 4;
#pragma unroll
    for (int nt = 0; nt < NTW; ++nt) {
        int n = (wv * NTW + nt) * 16 + r15;
        float bv = bias[n];
#pragma unroll
        for (int mt = 0; mt < MT; ++mt) acc[mt][nt] = (f4){bv, bv, bv, bv};
    }
#pragma unroll
    for (int ks = 0; ks < KSTEPS; ++ks) {
        s8v afr[MT];
#pragma unroll
        for (int mt = 0; mt < MT; ++mt) {
            int row = mt * 16 + r15;
            int byte = ((row * KP + ks * 32 + g * 8) * 2) ^ ((row & 7) << 4);
            afr[mt] = *(const s8v*)((const char*)A + byte);
        }
#pragma unroll
        for (int nt = 0; nt < NTW; ++nt) {
            int n = (wv * NTW + nt) * 16 + r15;
            s8v bfr = *(const s8v*)(Wg + n * KP + ks * 32 + g * 8);
#pragma unroll
            for (int mt = 0; mt < MT; ++mt)
                acc[mt][nt] = __builtin_amdgcn_mfma_f32_16x16x32_bf16(afr[mt], bfr, acc[mt][nt], 0, 0, 0);
        }
    }
}

template <int MT, int NTW, int CO>
__device__ __forceinline__ void store_lds(f4 (&acc)[MT][NTW], unsigned short* OUT, int lane, int wv) {
    const int r15 = lane & 15, g = lane >> 4;
#pragma unroll
    for (int mt = 0; mt < MT; ++mt)
#pragma unroll
        for (int nt = 0; nt < NTW; ++nt)
#pragma unroll
            for (int q = 0; q < 4; ++q) {
                int j = mt * 16 + g * 4 + q;
                int n = (wv * NTW + nt) * 16 + r15;
                float v = fmaxf(acc[mt][nt][q], 0.f);
                int byte = ((j * CO + n) * 2) ^ ((j & 7) << 4);
                *(unsigned short*)((char*)OUT + byte) = f2bf(v);
            }
}

// ---------------- fused ball query + gather + MFMA MLP + max ----------------
template <int S_, int C1, int C2, int C3>
__device__ __forceinline__ void msg_body(int bm, char* smem,
    const float* __restrict__ pts, const unsigned short* __restrict__ ftr,
    const float* __restrict__ cent,
    const unsigned short* __restrict__ W0, const float* __restrict__ B0,
    const unsigned short* __restrict__ W1, const float* __restrict__ B1,
    const unsigned short* __restrict__ W2, const float* __restrict__ B2,
    float* __restrict__ outf, int ch_off, float rr)
{
    constexpr int MT = S_ / 16;
    constexpr int KS1 = C1 / 32, KS2 = C2 / 32;
    constexpr int NW1 = C1 / 64, NW2 = C2 / 64, NW3 = C3 / 64;
    constexpr int HA = (S_ * 96 > S_ * C2) ? S_ * 96 : S_ * C2;
    unsigned short* hA = (unsigned short*)smem;
    unsigned short* hB = hA + HA;
    int* nbr = (int*)(hB + S_ * C1);
    int* wtot = nbr + S_;
    const int tid = threadIdx.x, lane = tid & 63, wv = tid >> 6;
    const int b = bm >> 9, m = bm & (MCENT - 1);
    const float cx = cent[bm * 3], cy = cent[bm * 3 + 1], cz = cent[bm * 3 + 2];
    const float* px = pts + b * 3 * NPTS;
    const float* py = px + NPTS;
    const float* pz = py + NPTS;

    // ---- ball query: first S smallest in-ball indices (ascending) ----
    unsigned mask = 0; int cnt = 0;
    {
#pragma clang fp contract(off)
#pragma unroll
        for (int k = 0; k < 8; ++k) {
            int n = tid * 8 + k;
            float dx = cx - px[n], dy = cy - py[n], dz = cz - pz[n];
            float d2 = dx * dx + dy * dy;
            d2 = d2 + dz * dz;
            if (d2 <= rr) { mask |= 1u << k; ++cnt; }
        }
    }
    int inc = cnt;
#pragma unroll
    for (int off = 1; off < 64; off <<= 1) {
        int t = __shfl_up(inc, off);
        if (lane >= off) inc += t;
    }
    if (lane == 63) wtot[wv] = inc;
    __syncthreads();
    int base = 0, tot = 0;
#pragma unroll
    for (int w = 0; w < 4; ++w) { int t = wtot[w]; tot += t; if (w < wv) base += t; }
    int pos = base + inc - cnt;
#pragma unroll
    for (int k = 0; k < 8; ++k) {
        if ((mask >> k) & 1) {
            if (pos < S_) nbr[pos] = tid * 8 + k;
            ++pos;
        }
    }
    __syncthreads();
    const int first = nbr[0];

    // ---- gather: rows = [feat(64) ; rel_xyz(3) ; pad -> 96] bf16, swizzled ----
    for (int e = tid; e < S_ * 8; e += 256) {
        int j = e >> 3, c8 = e & 7;
        int p = (j < tot) ? nbr[j] : first;
        s8v v = *(const s8v*)(ftr + (b * NPTS + p) * 64 + c8 * 8);
        int byte = ((j * 96 + c8 * 8) * 2) ^ ((j & 7) << 4);
        *(s8v*)((char*)hA + byte) = v;
    }
    for (int e = tid; e < S_ * 4; e += 256) {
        int j = e >> 2, q = e & 3;
        int p = (j < tot) ? nbr[j] : first;
        s8v v = {0, 0, 0, 0, 0, 0, 0, 0};
        if (q == 0) {
            v[0] = (short)f2bf(px[p] - cx);
            v[1] = (short)f2bf(py[p] - cy);
            v[2] = (short)f2bf(pz[p] - cz);
        }
        int byte = ((j * 96 + 64 + q * 8) * 2) ^ ((j & 7) << 4);
        *(s8v*)((char*)hA + byte) = v;
    }
    __syncthreads();

    // ---- MLP: 3 MFMA layers ----
    {
        f4 acc[MT][NW1];
        layer_mm<MT, 3, NW1>(hA, W0, B0, lane, wv, acc);
        store_lds<MT, NW1, C1>(acc, hB, lane, wv);
    }
    __syncthreads();
    {
        f4 acc[MT][NW2];
        layer_mm<MT, KS1, NW2>(hB, W1, B1, lane, wv, acc);
        store_lds<MT, NW2, C2>(acc, hA, lane, wv);
    }
    __syncthreads();
    {
        f4 acc[MT][NW3];
        layer_mm<MT, KS2, NW3>(hA, W2, B2, lane, wv, acc);
        const int r15 = lane & 15;
        float* dst = outf + b * 384 * MCENT + ch_off * MCENT + m;
#pragma unroll
        for (int nt = 0; nt < NW3; ++nt) {
            float mv = -1e30f;
#pragma unroll
            for (int mt = 0; mt < MT; ++mt)
#pragma unroll
                for (int q = 0; q < 4; ++q) mv = fmaxf(mv, acc[mt][nt][q]);
            mv = fmaxf(mv, __shfl_xor(mv, 16));
            mv = fmaxf(mv, __shfl_xor(mv, 32));
            float v = fmaxf(mv, 0.f);
            if (lane < 16) dst[((wv * NW3 + nt) * 16 + r15) * MCENT] = v;
        }
    }
}

__global__ __launch_bounds__(256) void msg_both(
    const float* __restrict__ pts, const unsigned short* __restrict__ ftr,
    const float* __restrict__ cent, const unsigned short* __restrict__ wp,
    const float* __restrict__ b00, const float* __restrict__ b01, const float* __restrict__ b02,
    const float* __restrict__ b10, const float* __restrict__ b11, const float* __restrict__ b12,
    float* __restrict__ outf, float rr0, float rr1)
{
    extern __shared__ __align__(16) char smem[];
    if (blockIdx.x < BATCH * MCENT)
        msg_body<32, 64, 64, 128>(blockIdx.x, smem, pts, ftr, cent,
                                  wp + 0, b00, wp + 6144, b01, wp + 10240, b02, outf, 0, rr0);
    else
        msg_body<64, 128, 128, 256>(blockIdx.x - BATCH * MCENT, smem, pts, ftr, cent,
                                    wp + 18432, b10, wp + 30720, b11, wp + 47104, b12, outf, 128, rr1);
}

extern "C" void kernel_launch(void* const* d_in, const int* in_sizes, int n_in,
                              void* d_out, int out_size, void* d_ws, size_t ws_size,
                              hipStream_t stream) {
    const float* pts  = (const float*)d_in[0];
    const float* feats = (const float*)d_in[1];
    const float* w00 = (const float*)d_in[2];  const float* b00 = (const float*)d_in[3];
    const float* w01 = (const float*)d_in[4];  const float* b01 = (const float*)d_in[5];
    const float* w02 = (const float*)d_in[6];  const float* b02 = (const float*)d_in[7];
    const float* w10 = (const float*)d_in[8];  const float* b10 = (const float*)d_in[9];
    const float* w11 = (const float*)d_in[10]; const float* b11 = (const float*)d_in[11];
    const float* w12 = (const float*)d_in[12]; const float* b12 = (const float*)d_in[13];
    float* out = (float*)d_out;
    char* ws = (char*)d_ws;
    float* cent = (float*)ws;                                       // 24576 B
    unsigned short* ftr = (unsigned short*)(ws + 24576);            // 1048576 B
    unsigned short* wp  = (unsigned short*)(ws + 24576 + 1048576);  // 159744 B

    hipLaunchKernelGGL(fps_prep, dim3(65), dim3(1024), 0, stream,
                       pts, feats, w00, w01, w02, w10, w11, w12, cent, ftr, wp, out);
    float* outf = out + BATCH * 3 * MCENT;
    const float RR0 = (float)(0.2 * 0.2);
    const float RR1 = (float)(0.4 * 0.4);
    hipLaunchKernelGGL(msg_both, dim3(2 * BATCH * MCENT), dim3(256), 33040, stream,
                       pts, ftr, cent, wp, b00, b01, b02, b10, b11, b12, outf, RR0, RR1);
}

// Round 13
// 291.295 us; speedup vs baseline: 1.9281x; 1.9281x over previous
//
#include <hip/hip_runtime.h>

#define NPTS 2048
#define BATCH 4
#define CFEAT 64
#define MCENT 512

typedef float f4 __attribute__((ext_vector_type(4)));
typedef float f2 __attribute__((ext_vector_type(2)));
typedef short s8v __attribute__((ext_vector_type(8)));

__device__ __forceinline__ unsigned short f2bf(float x) {
    unsigned u = __float_as_uint(x);
    return (unsigned short)((u + 0x7fffu + ((u >> 16) & 1u)) >> 16);
}

template <int CTRL>
__device__ __forceinline__ float dpp_max_step(float v) {
    int t = __builtin_amdgcn_update_dpp(0, __float_as_int(v), CTRL, 0xf, 0xf, true);
    return fmaxf(v, __int_as_float(t));
}

__device__ __forceinline__ float readlane_f(float v, int l) {
    return __int_as_float(__builtin_amdgcn_readlane(__float_as_int(v), l));
}

// ---------------- weight packing (bf16, padded, layer0 column-permuted) ----------------
// wp (ushort elems): s0l0@0 (64x96), s0l1@6144 (64x64), s0l2@10240 (128x64),
// s1l0@18432 (128x96), s1l1@30720 (128x128), s1l2@47104 (256x128) -> 79872
template <int COUT, int CIN, int KPW, bool PERM>
__device__ void pack_seg(const float* w, unsigned short* dst, int start, int stride) {
    for (int i = start; i < COUT * KPW; i += stride) {
        int o = i / KPW, k = i - o * KPW;
        float v = 0.f;
        if (PERM) {  // packed col k: [0,64)=feat(src 3+k), [64,67)=xyz(src k-64), rest 0
            if (k < 64) v = w[o * CIN + 3 + k];
            else if (k < 67) v = w[o * CIN + (k - 64)];
        } else {
            if (k < CIN) v = w[o * CIN + k];
        }
        dst[i] = f2bf(v);
    }
}

// ---------------- FPS (blocks 0..3, 4 waves) + prep (blocks 4..67) ----------------
__global__ __launch_bounds__(256, 1) void fps_prep(
    const float* __restrict__ pts, const float* __restrict__ feats,
    const float* w00, const float* w01, const float* w02,
    const float* w10, const float* w11, const float* w12,
    float* cent, unsigned short* ftr, unsigned short* wp, float* out)
{
    const int tid = threadIdx.x;
    if (blockIdx.x >= 4) {
        const int stride = 64 * 256;
        const int start = (blockIdx.x - 4) * 256 + tid;
        for (int i = start; i < BATCH * NPTS * CFEAT; i += stride) {
            int c = i & 63, n = (i >> 6) & (NPTS - 1), b = i >> 17;
            ftr[i] = f2bf(feats[(b * CFEAT + c) * NPTS + n]);
        }
        pack_seg<64, 67, 96, true>(w00, wp + 0, start, stride);
        pack_seg<64, 64, 64, false>(w01, wp + 6144, start, stride);
        pack_seg<128, 64, 64, false>(w02, wp + 10240, start, stride);
        pack_seg<128, 67, 96, true>(w10, wp + 18432, start, stride);
        pack_seg<128, 128, 128, false>(w11, wp + 30720, start, stride);
        pack_seg<256, 128, 128, false>(w12, wp + 47104, start, stride);
        return;
    }
    const int b = blockIdx.x;
    const int lane = tid & 63, wv = tid >> 6;
    const float* px = pts + b * 3 * NPTS;
    const float* py = px + NPTS;
    const float* pz = py + NPTS;
    __shared__ __align__(16) float4 slotq[8 * 2];   // [parity*4+wave], stride-2 to spread banks
    __shared__ __align__(16) float4 scent[MCENT];   // centroid shadow: no global stores in loop

    __builtin_amdgcn_s_setprio(3);   // protect FPS issue while prep blocks co-reside

    // wave wv owns points [wv*512, wv*512+512); lane owns 8 (4 f2 pairs, even/odd)
    const int base = wv * 512 + lane * 8;
    f2 rx[4], ry[4], rz[4], rd[4];
#pragma unroll
    for (int i = 0; i < 4; ++i) {
        rx[i] = *(const f2*)(px + base + 2 * i);
        ry[i] = *(const f2*)(py + base + 2 * i);
        rz[i] = *(const f2*)(pz + base + 2 * i);
        rd[i] = (f2){1e10f, 1e10f};
    }
    float cx = px[0], cy = py[0], cz = pz[0];
    int par = 0;
    for (int m = 0; m < MCENT; ++m) {
        if (tid == 0) scent[m] = make_float4(cx, cy, cz, 0.f);  // LDS only: no vmcnt drain at barrier
        {
#pragma clang fp contract(off)
            f2 c2x = {cx, cx}, c2y = {cy, cy}, c2z = {cz, cz};
#pragma unroll
            for (int i = 0; i < 4; ++i) {
                f2 dx = rx[i] - c2x, dy = ry[i] - c2y, dz = rz[i] - c2z;
                f2 d2 = dx * dx + dy * dy;   // contract off: numpy order
                d2 = d2 + dz * dz;
                f2 old = rd[i];
                f2 nd;
                nd.x = fminf(old.x, d2.x);
                nd.y = fminf(old.y, d2.y);
                rd[i] = nd;
            }
        }
        // value-only max tree over lane's 8 points (depth 3, max3-fusable)
        float n0 = rd[0].x, n1 = rd[0].y, n2 = rd[1].x, n3 = rd[1].y;
        float n4 = rd[2].x, n5 = rd[2].y, n6 = rd[3].x, n7 = rd[3].y;
        float bv = fmaxf(fmaxf(fmaxf(n0, n1), fmaxf(n2, n3)),
                         fmaxf(fmaxf(n4, n5), fmaxf(n6, n7)));
        // coord select: descending-k scan -> smallest matching k wins (off critical path)
        float ox = rx[3].y, oy = ry[3].y, oz = rz[3].y;
        {
            float ndv[8] = {n0, n1, n2, n3, n4, n5, n6, n7};
#pragma unroll
            for (int k = 6; k >= 0; --k) {
                bool t = (ndv[k] == bv);
                float nx = (k & 1) ? rx[k >> 1].y : rx[k >> 1].x;
                float ny = (k & 1) ? ry[k >> 1].y : ry[k >> 1].x;
                float nz = (k & 1) ? rz[k >> 1].y : rz[k >> 1].x;
                ox = t ? nx : ox; oy = t ? ny : oy; oz = t ? nz : oz;
            }
        }
        // DPP wave max -> lane 63
        float v = bv;
        v = dpp_max_step<0x111>(v);
        v = dpp_max_step<0x112>(v);
        v = dpp_max_step<0x114>(v);
        v = dpp_max_step<0x118>(v);
        v = dpp_max_step<0x142>(v);
        v = dpp_max_step<0x143>(v);
        float wmax = readlane_f(v, 63);
        unsigned long long cand = __ballot(bv == wmax);
        int wl = __ffsll(cand) - 1;          // lowest lane = smallest global index
        if (lane == wl) slotq[(par * 4 + wv) * 2] = make_float4(bv, ox, oy, oz);
        __syncthreads();                      // one barrier per step (parity dbuf)
        float4 s0 = slotq[(par * 4 + 0) * 2];
        float4 s1 = slotq[(par * 4 + 1) * 2];
        float4 s2 = slotq[(par * 4 + 2) * 2];
        float4 s3 = slotq[(par * 4 + 3) * 2];
        // tie-break = wave order = index order; strict > keeps lower wave on tie
        float4 c01 = (s1.x > s0.x) ? s1 : s0;
        float4 c23 = (s3.x > s2.x) ? s3 : s2;
        float4 cc  = (c23.x > c01.x) ? c23 : c01;
        cx = cc.y; cy = cc.z; cz = cc.w;
        par ^= 1;
    }
    __syncthreads();
    // bulk write centroids (cent for msg kernel, out for result)
    float* outc = out + b * 3 * MCENT;
    for (int m = tid; m < MCENT; m += 256) {
        float4 c = scent[m];
        float* cw = cent + (b * MCENT + m) * 3;
        cw[0] = c.x; cw[1] = c.y; cw[2] = c.z;
        outc[m] = c.x; outc[MCENT + m] = c.y; outc[2 * MCENT + m] = c.z;
    }
}

// ---------------- MFMA MLP layer ----------------
template <int MT, int KSTEPS, int NTW>
__device__ __forceinline__ void layer_mm(const unsigned short* A, const unsigned short* __restrict__ Wg,
                                         const float* __restrict__ bias, int lane, int wv,
                                         f4 (&acc)[MT][NTW])
{
    constexpr int KP = KSTEPS * 32;
    const int r15 = lane & 15, g = lane >> 4;
#pragma unroll
    for (int nt = 0; nt < NTW; ++nt) {
        int n = (wv * NTW + nt) * 16 + r15;
        float bv = bias[n];
#pragma unroll
        for (int mt = 0; mt < MT; ++mt) acc[mt][nt] = (f4){bv, bv, bv, bv};
    }
#pragma unroll
    for (int ks = 0; ks < KSTEPS; ++ks) {
        s8v afr[MT];
#pragma unroll
        for (int mt = 0; mt < MT; ++mt) {
            int row = mt * 16 + r15;
            int byte = ((row * KP + ks * 32 + g * 8) * 2) ^ ((row & 7) << 4);
            afr[mt] = *(const s8v*)((const char*)A + byte);
        }
#pragma unroll
        for (int nt = 0; nt < NTW; ++nt) {
            int n = (wv * NTW + nt) * 16 + r15;
            s8v bfr = *(const s8v*)(Wg + n * KP + ks * 32 + g * 8);
#pragma unroll
            for (int mt = 0; mt < MT; ++mt)
                acc[mt][nt] = __builtin_amdgcn_mfma_f32_16x16x32_bf16(afr[mt], bfr, acc[mt][nt], 0, 0, 0);
        }
    }
}

template <int MT, int NTW, int CO>
__device__ __forceinline__ void store_lds(f4 (&acc)[MT][NTW], unsigned short* OUT, int lane, int wv) {
    const int r15 = lane & 15, g = lane >> 4;
#pragma unroll
    for (int mt = 0; mt < MT; ++mt)
#pragma unroll
        for (int nt = 0; nt < NTW; ++nt)
#pragma unroll
            for (int q = 0; q < 4; ++q) {
                int j = mt * 16 + g * 4 + q;
                int n = (wv * NTW + nt) * 16 + r15;
                float v = fmaxf(acc[mt][nt][q], 0.f);
                int byte = ((j * CO + n) * 2) ^ ((j & 7) << 4);
                *(unsigned short*)((char*)OUT + byte) = f2bf(v);
            }
}

// ---------------- fused ball query + gather + MFMA MLP + max ----------------
template <int S_, int C1, int C2, int C3>
__device__ __forceinline__ void msg_body(int bm, char* smem,
    const float* __restrict__ pts, const unsigned short* __restrict__ ftr,
    const float* __restrict__ cent,
    const unsigned short* __restrict__ W0, const float* __restrict__ B0,
    const unsigned short* __restrict__ W1, const float* __restrict__ B1,
    const unsigned short* __restrict__ W2, const float* __restrict__ B2,
    float* __restrict__ outf, int ch_off, float rr)
{
    constexpr int MT = S_ / 16;
    constexpr int KS1 = C1 / 32, KS2 = C2 / 32;
    constexpr int NW1 = C1 / 64, NW2 = C2 / 64, NW3 = C3 / 64;
    constexpr int HA = (S_ * 96 > S_ * C2) ? S_ * 96 : S_ * C2;
    unsigned short* hA = (unsigned short*)smem;
    unsigned short* hB = hA + HA;
    int* nbr = (int*)(hB + S_ * C1);
    int* wtot = nbr + S_;
    const int tid = threadIdx.x, lane = tid & 63, wv = tid >> 6;
    const int b = bm >> 9, m = bm & (MCENT - 1);
    const float cx = cent[bm * 3], cy = cent[bm * 3 + 1], cz = cent[bm * 3 + 2];
    const float* px = pts + b * 3 * NPTS;
    const float* py = px + NPTS;
    const float* pz = py + NPTS;

    // ---- ball query: first S smallest in-ball indices (ascending) ----
    unsigned mask = 0; int cnt = 0;
    {
#pragma clang fp contract(off)
#pragma unroll
        for (int k = 0; k < 8; ++k) {
            int n = tid * 8 + k;
            float dx = cx - px[n], dy = cy - py[n], dz = cz - pz[n];
            float d2 = dx * dx + dy * dy;
            d2 = d2 + dz * dz;
            if (d2 <= rr) { mask |= 1u << k; ++cnt; }
        }
    }
    int inc = cnt;
#pragma unroll
    for (int off = 1; off < 64; off <<= 1) {
        int t = __shfl_up(inc, off);
        if (lane >= off) inc += t;
    }
    if (lane == 63) wtot[wv] = inc;
    __syncthreads();
    int base = 0, tot = 0;
#pragma unroll
    for (int w = 0; w < 4; ++w) { int t = wtot[w]; tot += t; if (w < wv) base += t; }
    int pos = base + inc - cnt;
#pragma unroll
    for (int k = 0; k < 8; ++k) {
        if ((mask >> k) & 1) {
            if (pos < S_) nbr[pos] = tid * 8 + k;
            ++pos;
        }
    }
    __syncthreads();
    const int first = nbr[0];

    // ---- gather: rows = [feat(64) ; rel_xyz(3) ; pad -> 96] bf16, swizzled ----
    for (int e = tid; e < S_ * 8; e += 256) {
        int j = e >> 3, c8 = e & 7;
        int p = (j < tot) ? nbr[j] : first;
        s8v v = *(const s8v*)(ftr + (b * NPTS + p) * 64 + c8 * 8);
        int byte = ((j * 96 + c8 * 8) * 2) ^ ((j & 7) << 4);
        *(s8v*)((char*)hA + byte) = v;
    }
    for (int e = tid; e < S_ * 4; e += 256) {
        int j = e >> 2, q = e & 3;
        int p = (j < tot) ? nbr[j] : first;
        s8v v = {0, 0, 0, 0, 0, 0, 0, 0};
        if (q == 0) {
            v[0] = (short)f2bf(px[p] - cx);
            v[1] = (short)f2bf(py[p] - cy);
            v[2] = (short)f2bf(pz[p] - cz);
        }
        int byte = ((j * 96 + 64 + q * 8) * 2) ^ ((j & 7) << 4);
        *(s8v*)((char*)hA + byte) = v;
    }
    __syncthreads();

    // ---- MLP: 3 MFMA layers ----
    {
        f4 acc[MT][NW1];
        layer_mm<MT, 3, NW1>(hA, W0, B0, lane, wv, acc);
        store_lds<MT, NW1, C1>(acc, hB, lane, wv);
    }
    __syncthreads();
    {
        f4 acc[MT][NW2];
        layer_mm<MT, KS1, NW2>(hB, W1, B1, lane, wv, acc);
        store_lds<MT, NW2, C2>(acc, hA, lane, wv);
    }
    __syncthreads();
    {
        f4 acc[MT][NW3];
        layer_mm<MT, KS2, NW3>(hA, W2, B2, lane, wv, acc);
        const int r15 = lane & 15;
        float* dst = outf + b * 384 * MCENT + ch_off * MCENT + m;
#pragma unroll
        for (int nt = 0; nt < NW3; ++nt) {
            float mv = -1e30f;
#pragma unroll
            for (int mt = 0; mt < MT; ++mt)
#pragma unroll
                for (int q = 0; q < 4; ++q) mv = fmaxf(mv, acc[mt][nt][q]);
            mv = fmaxf(mv, __shfl_xor(mv, 16));
            mv = fmaxf(mv, __shfl_xor(mv, 32));
            float v = fmaxf(mv, 0.f);
            if (lane < 16) dst[((wv * NW3 + nt) * 16 + r15) * MCENT] = v;
        }
    }
}

__global__ __launch_bounds__(256) void msg_both(
    const float* __restrict__ pts, const unsigned short* __restrict__ ftr,
    const float* __restrict__ cent, const unsigned short* __restrict__ wp,
    const float* __restrict__ b00, const float* __restrict__ b01, const float* __restrict__ b02,
    const float* __restrict__ b10, const float* __restrict__ b11, const float* __restrict__ b12,
    float* __restrict__ outf, float rr0, float rr1)
{
    extern __shared__ __align__(16) char smem[];
    if (blockIdx.x < BATCH * MCENT)
        msg_body<32, 64, 64, 128>(blockIdx.x, smem, pts, ftr, cent,
                                  wp + 0, b00, wp + 6144, b01, wp + 10240, b02, outf, 0, rr0);
    else
        msg_body<64, 128, 128, 256>(blockIdx.x - BATCH * MCENT, smem, pts, ftr, cent,
                                    wp + 18432, b10, wp + 30720, b11, wp + 47104, b12, outf, 128, rr1);
}

extern "C" void kernel_launch(void* const* d_in, const int* in_sizes, int n_in,
                              void* d_out, int out_size, void* d_ws, size_t ws_size,
                              hipStream_t stream) {
    const float* pts  = (const float*)d_in[0];
    const float* feats = (const float*)d_in[1];
    const float* w00 = (const float*)d_in[2];  const float* b00 = (const float*)d_in[3];
    const float* w01 = (const float*)d_in[4];  const float* b01 = (const float*)d_in[5];
    const float* w02 = (const float*)d_in[6];  const float* b02 = (const float*)d_in[7];
    const float* w10 = (const float*)d_in[8];  const float* b10 = (const float*)d_in[9];
    const float* w11 = (const float*)d_in[10]; const float* b11 = (const float*)d_in[11];
    const float* w12 = (const float*)d_in[12]; const float* b12 = (const float*)d_in[13];
    float* out = (float*)d_out;
    char* ws = (char*)d_ws;
    float* cent = (float*)ws;                                       // 24576 B
    unsigned short* ftr = (unsigned short*)(ws + 24576);            // 1048576 B
    unsigned short* wp  = (unsigned short*)(ws + 24576 + 1048576);  // 159744 B

    hipLaunchKernelGGL(fps_prep, dim3(68), dim3(256), 0, stream,
                       pts, feats, w00, w01, w02, w10, w11, w12, cent, ftr, wp, out);
    float* outf = out + BATCH * 3 * MCENT;
    const float RR0 = (float)(0.2 * 0.2);
    const float RR1 = (float)(0.4 * 0.4);
    hipLaunchKernelGGL(msg_both, dim3(2 * BATCH * MCENT), dim3(256), 33040, stream,
                       pts, ftr, cent, wp, b00, b01, b02, b10, b11, b12, outf, RR0, RR1);
}